// Round 8
// baseline (228.973 us; speedup 1.0000x reference)
//
#include <hip/hip_runtime.h>
#include <hip/hip_bf16.h>

// SizeInvBlock: upsample3x(nearest) -> per-sample dilated 3x3 conv -> maxpool3 -> BN(train) -> relu
// Factorization: conv on the 3x-upsampled image only samples original 32x32 pixels:
//   out[o,y,x] = bias[o] + sum_{ki,kj} P[ki*3+kj][r_ki(y), c_kj(x)],
//   P = A9[9x64] @ XbT_b[64x1024]  (per (o,b) pair)
// R8: fusion v2 (no T tensor, no k1). Fixes R6's failure modes:
//   - 512 thr (8-wave barriers), 2 outputs/thread
//   - 16 MFMA/wave, B-loads double-buffered + first load issued before zero-fill
//   - scatter per n-tile (acc live = 1 f32x4) -> low VGPR -> 3 blocks/CU
// Gather network and scatter mapping identical to the R6/R7-verified code.
//
// ws layout (bytes):
//   [0,      1024)    stats: sum[128], sumsq[128] (f32, atomic)
//   [4096,   266240)  A2 bf16 [128 o][16 m][64 c]  (m=ki*3+kj, rows 9..15 zero)
//   [4194304,12582912) XbT bf16 [64 b][1024 n][64 c]

typedef __attribute__((ext_vector_type(8))) short bf16x8;
typedef __attribute__((ext_vector_type(4))) float f32x4;
typedef __attribute__((ext_vector_type(8))) unsigned short us8;

__device__ __forceinline__ unsigned short f2bf(float f) {
    unsigned u = __float_as_uint(f);
    u += 0x7fffu + ((u >> 16) & 1u);
    return (unsigned short)(u >> 16);
}
__device__ __forceinline__ int floordiv3(int t) {
    return (t >= 0) ? (t / 3) : -((2 - t) / 3);
}

// ---- K0a: X fp32 [b][c][1024] -> XbT bf16 [b][n][c] ----------------------
__global__ __launch_bounds__(256) void k0_x(const float* __restrict__ x,
                                            unsigned short* __restrict__ xbt) {
    const int tid = threadIdx.x;
    const int n = blockIdx.x * 64 + (tid & 63);
    const int cg = tid >> 6;
    const int b = blockIdx.y;
    #pragma unroll
    for (int j2 = 0; j2 < 2; ++j2) {
        int c8 = cg * 2 + j2;                     // 0..7
        us8 r;
        #pragma unroll
        for (int j = 0; j < 8; ++j)
            r[j] = f2bf(x[(((b << 6) + c8 * 8 + j) << 10) + n]);
        *reinterpret_cast<us8*>(xbt + ((size_t)(b << 10) + n) * 64 + c8 * 8) = r;
    }
}

// ---- K0b: W fp32 [o][c][ki][kj] -> A2 bf16 [o][16][64], rows 9..15 = 0 ---
__global__ __launch_bounds__(256) void k0_w(const float* __restrict__ w,
                                            unsigned short* __restrict__ A2) {
    int gid = blockIdx.x * 256 + threadIdx.x;  // < 131072
    int o = gid >> 10, m = (gid >> 6) & 15, c = gid & 63;
    A2[gid] = (m < 9) ? f2bf(w[(o * 64 + c) * 9 + m]) : (unsigned short)0;
}

// ---- K2: fused MFMA(9x64 @ 64x1024) -> LDS planes -> 36-tap gather -------
// grid (o=128, b=64), 512 thr (8 waves). LDS: 9 planes of 33 rows x 40 f32
// at stride PLS=1322 (R6-verified), 4-col pads both sides, row 32 = zeros.
#define PLS 1322
__global__ __launch_bounds__(512, 4) void k2_fused(const unsigned short* __restrict__ XbT,
                                                   const unsigned short* __restrict__ A2,
                                                   const float* __restrict__ bias,
                                                   const int* __restrict__ hh,
                                                   const int* __restrict__ ww,
                                                   float* __restrict__ out,
                                                   float* __restrict__ stats) {
    __shared__ float lt[9 * PLS + 4];   // 47616 B
    __shared__ float red[16];
    const int tid = threadIdx.x;
    const int o = blockIdx.x, b = blockIdx.y;
    const int wave = tid >> 6, lane = tid & 63;
    const int quad = lane >> 4, l15 = lane & 15;

    // A-frags (2 KB per o, L2-hot: each o-slice read by 64 b-blocks)
    const bf16x8 aF0 = *reinterpret_cast<const bf16x8*>(A2 + o * 1024 + l15 * 64 + quad * 8);
    const bf16x8 aF1 = *reinterpret_cast<const bf16x8*>(A2 + o * 1024 + l15 * 64 + 32 + quad * 8);

    // first B-load issued BEFORE zero-fill so L2 latency hides behind it
    const unsigned short* xb = XbT + ((size_t)b * 1024) * 64;
    const unsigned short* pfirst = xb + (size_t)(wave * 8 * 16 + l15) * 64 + quad * 8;
    bf16x8 cb0 = *reinterpret_cast<const bf16x8*>(pfirst);
    bf16x8 cb1 = *reinterpret_cast<const bf16x8*>(pfirst + 32);

    // zero pad columns (rows 0..31, cols {0..3, 36..39}) of each plane
    #pragma unroll
    for (int it = 0; it < 5; ++it) {
        int i = it * 512 + tid;
        if (i < 9 * 32 * 8) {
            int pr = i >> 3, c = i & 7;
            int kk = pr >> 5, r = pr & 31;
            lt[kk * PLS + r * 40 + (c < 4 ? c : c + 32)] = 0.f;
        }
    }
    // zero row 32 of each plane; slack zeroed separately (in-bounds)
    if (tid < 9 * 40) {
        int kk = tid / 40, c = tid - kk * 40;
        lt[kk * PLS + 32 * 40 + c] = 0.f;
    }
    if (tid < 4) lt[9 * PLS + tid] = 0.f;

    // GEMM: 8 n-tiles per wave, double-buffered B, scatter per tile
    #pragma unroll
    for (int t = 0; t < 8; ++t) {
        const int nt = wave * 8 + t;
        bf16x8 nb0, nb1;
        if (t < 7) {
            const unsigned short* pp = xb + (size_t)((nt + 1) * 16 + l15) * 64 + quad * 8;
            nb0 = *reinterpret_cast<const bf16x8*>(pp);
            nb1 = *reinterpret_cast<const bf16x8*>(pp + 32);
        }
        f32x4 acc = {};
        acc = __builtin_amdgcn_mfma_f32_16x16x32_bf16(aF0, cb0, acc, 0, 0, 0);
        acc = __builtin_amdgcn_mfma_f32_16x16x32_bf16(aF1, cb1, acc, 0, 0, 0);
        // C/D: col = lane&15 (n in tile), row = quad*4 + reg (m = kikj)
        const int n0 = nt * 16;
        float* dst = &lt[(n0 >> 5) * 40 + 4 + (n0 & 31) + l15];
        #pragma unroll
        for (int rg = 0; rg < 4; ++rg) {
            int m = quad * 4 + rg;
            if (m < 9) dst[m * PLS] = acc[rg];
        }
        cb0 = nb0; cb1 = nb1;
    }
    __syncthreads();

    // --- gather phase: 2 outputs/thread (p and p+16) ----------------------
    int dh = 96 / hh[b]; if (dh < 1) dh = 1;
    int dw = 96 / ww[b]; if (dw < 1) dw = 1;
    const int q = tid & 31, pbase = tid >> 5;   // pbase 0..15
    const int qoff = q + 4;

    // ki=1 / kj=1 have t0=0 -> base 0, selector always 0.
    const int g0 = floordiv3(-dh), g2 = floordiv3(dh);
    const int f0 = floordiv3(-dw), f2 = floordiv3(dw);
    int r0sel[3], r2sel[3], c0sel[3], c2sel[3];    // block-uniform {0,1}
    #pragma unroll
    for (int t = 0; t < 3; ++t) {
        r0sel[t] = floordiv3(t - dh) - g0;
        r2sel[t] = floordiv3(t + dh) - g2;
        c0sel[t] = floordiv3(t - dw) - f0;
        c2sel[t] = floordiv3(t + dw) - f2;
    }
    const float bias_o = bias[o];
    float s1 = 0.f, s2 = 0.f;

    #pragma unroll
    for (int half = 0; half < 2; ++half) {
        const int p = pbase + half * 16;
        int rA0 = p + g0;     rA0 = ((unsigned)rA0 < 32u) ? rA0 : 32;
        int rB0 = p + g0 + 1; rB0 = ((unsigned)rB0 < 32u) ? rB0 : 32;
        int rA2 = p + g2;     rA2 = ((unsigned)rA2 < 32u) ? rA2 : 32;
        int rB2 = p + g2 + 1; rB2 = ((unsigned)rB2 < 32u) ? rB2 : 32;

        float u0[2][3], u1[3], u2[2][3];
        {   // ki = 0 (planes 0..2)
            const float* pl0 = &lt[0 * PLS + qoff + f0];
            const float* pl1 = &lt[1 * PLS + qoff];
            const float* pl2 = &lt[2 * PLS + qoff + f2];
            float pA0a = pl0[rA0 * 40], pA0b = pl0[rA0 * 40 + 1];
            float pB0a = pl0[rB0 * 40], pB0b = pl0[rB0 * 40 + 1];
            float sA   = pl1[rA0 * 40], sB   = pl1[rB0 * 40];
            float pA2a = pl2[rA0 * 40], pA2b = pl2[rA0 * 40 + 1];
            float pB2a = pl2[rB0 * 40], pB2b = pl2[rB0 * 40 + 1];
            #pragma unroll
            for (int x3 = 0; x3 < 3; ++x3) {
                u0[0][x3] = (c0sel[x3] ? pA0b : pA0a) + sA + (c2sel[x3] ? pA2b : pA2a);
                u0[1][x3] = (c0sel[x3] ? pB0b : pB0a) + sB + (c2sel[x3] ? pB2b : pB2a);
            }
        }
        {   // ki = 1 (planes 3..5), row p only
            const float* pl0 = &lt[3 * PLS + qoff + f0];
            const float* pl1 = &lt[4 * PLS + qoff];
            const float* pl2 = &lt[5 * PLS + qoff + f2];
            float pa = pl0[p * 40], pb = pl0[p * 40 + 1];
            float s  = pl1[p * 40];
            float ra = pl2[p * 40], rb = pl2[p * 40 + 1];
            #pragma unroll
            for (int x3 = 0; x3 < 3; ++x3)
                u1[x3] = (c0sel[x3] ? pb : pa) + s + (c2sel[x3] ? rb : ra);
        }
        {   // ki = 2 (planes 6..8)
            const float* pl0 = &lt[6 * PLS + qoff + f0];
            const float* pl1 = &lt[7 * PLS + qoff];
            const float* pl2 = &lt[8 * PLS + qoff + f2];
            float pA0a = pl0[rA2 * 40], pA0b = pl0[rA2 * 40 + 1];
            float pB0a = pl0[rB2 * 40], pB0b = pl0[rB2 * 40 + 1];
            float sA   = pl1[rA2 * 40], sB   = pl1[rB2 * 40];
            float pA2a = pl2[rA2 * 40], pA2b = pl2[rA2 * 40 + 1];
            float pB2a = pl2[rB2 * 40], pB2b = pl2[rB2 * 40 + 1];
            #pragma unroll
            for (int x3 = 0; x3 < 3; ++x3) {
                u2[0][x3] = (c0sel[x3] ? pA0b : pA0a) + sA + (c2sel[x3] ? pA2b : pA2a);
                u2[1][x3] = (c0sel[x3] ? pB0b : pB0a) + sB + (c2sel[x3] ? pB2b : pB2a);
            }
        }

        float best = -3.4e38f;
        #pragma unroll
        for (int y3 = 0; y3 < 3; ++y3)
            #pragma unroll
            for (int x3 = 0; x3 < 3; ++x3) {
                float s = (r0sel[y3] ? u0[1][x3] : u0[0][x3])
                        + u1[x3]
                        + (r2sel[y3] ? u2[1][x3] : u2[0][x3]);
                best = fmaxf(best, s);
            }
        float val = best + bias_o;
        out[(((size_t)b * 128 + o) * 32 + p) * 32 + q] = val;
        s1 += val;
        s2 += val * val;
    }

    // stats: wave reduce -> LDS -> block reduce -> 2 atomics
    #pragma unroll
    for (int m = 32; m >= 1; m >>= 1) {
        s1 += __shfl_xor(s1, m, 64);
        s2 += __shfl_xor(s2, m, 64);
    }
    if ((tid & 63) == 0) {
        red[wave] = s1;
        red[8 + wave] = s2;
    }
    __syncthreads();
    if (tid < 64) {
        float a1 = (tid < 8) ? red[tid] : 0.f;
        float a2 = (tid < 8) ? red[8 + tid] : 0.f;
        #pragma unroll
        for (int m = 4; m >= 1; m >>= 1) {
            a1 += __shfl_xor(a1, m, 64);
            a2 += __shfl_xor(a2, m, 64);
        }
        if (tid == 0) {
            atomicAdd(&stats[o], a1);
            atomicAdd(&stats[128 + o], a2);
        }
    }
}

// ---- K3: BN finalize + affine + relu, in-place on d_out ------------------
__global__ __launch_bounds__(256) void k3_bn(float4* __restrict__ out,
                                             const float* __restrict__ stats,
                                             const float* __restrict__ gamma,
                                             const float* __restrict__ beta) {
    int i4 = blockIdx.x * 256 + threadIdx.x;   // 0..2097151
    int o = (i4 >> 8) & 127;
    const float invN = 1.0f / 65536.0f;
    float mean = stats[o] * invN;
    float var = stats[128 + o] * invN - mean * mean;
    float inv = rsqrtf(var + 1e-5f);
    float sc = gamma[o] * inv;
    float sh = beta[o] - mean * sc;
    float4 v = out[i4];
    v.x = fmaxf(fmaf(v.x, sc, sh), 0.f);
    v.y = fmaxf(fmaf(v.y, sc, sh), 0.f);
    v.z = fmaxf(fmaf(v.z, sc, sh), 0.f);
    v.w = fmaxf(fmaf(v.w, sc, sh), 0.f);
    out[i4] = v;
}

extern "C" void kernel_launch(void* const* d_in, const int* in_sizes, int n_in,
                              void* d_out, int out_size, void* d_ws, size_t ws_size,
                              hipStream_t stream) {
    const float* x     = (const float*)d_in[0];
    const int*   h     = (const int*)d_in[1];
    const int*   wd    = (const int*)d_in[2];
    const float* wt    = (const float*)d_in[3];
    const float* bias  = (const float*)d_in[4];
    const float* gamma = (const float*)d_in[5];
    const float* beta  = (const float*)d_in[6];
    float* out = (float*)d_out;
    char* ws = (char*)d_ws;

    float*          stats = (float*)(ws + 0);
    unsigned short* A2    = (unsigned short*)(ws + 4096);
    unsigned short* XbT   = (unsigned short*)(ws + 4194304);

    hipMemsetAsync(stats, 0, 1024, stream);
    k0_x<<<dim3(16, 64), 256, 0, stream>>>(x, XbT);
    k0_w<<<512, 256, 0, stream>>>(wt, A2);
    k2_fused<<<dim3(128, 64), 512, 0, stream>>>(XbT, A2, bias, h, wd, out, stats);
    k3_bn<<<8192, 256, 0, stream>>>((float4*)out, stats, gamma, beta);
}

// Round 9
// 164.995 us; speedup vs baseline: 1.3878x; 1.3878x over previous
//
#include <hip/hip_runtime.h>
#include <hip/hip_bf16.h>

// SizeInvBlock: upsample3x(nearest) -> per-sample dilated 3x3 conv -> maxpool3 -> BN(train) -> relu
// Factorization: conv on the 3x-upsampled image only samples original 32x32 pixels:
//   out[o,y,x] = bias[o] + sum_{ki,kj} T[kikj][o, r_ki(y), c_kj(x)]
//   T[kikj][o,i,j] = sum_c W[o,c,ki,kj] * X[c,i,j]   (one GEMM, 9x fewer FLOPs than direct conv)
// R9: fusion abandoned (R6/R8 both latency-dead). R5 split + three deltas:
//   - k2: 512 thr x 2 outputs/thread (R8's verified gather phase on R5's staging)
//   - k1: R5 verbatim (best measured variant)
//   - k0_x/k0_w/stats-zero merged into one dispatch; memset dropped (6 -> 4 launches)
//
// ws layout (bytes):
//   [0,      1024)    stats: sum[128], sumsq[128] (f32, atomic; zeroed by k0_all)
//   [4096,   151552)  A bf16 [1152][64]   (m = (ki*3+kj)*128 + o, k = cin)
//   [151552, 8540160) XbT bf16 [64 b][1024 n][64 c]
//   [8540160,159535104) T bf16 [1152][65536]  (n = b*1024 + i*32 + j)

typedef __attribute__((ext_vector_type(8))) short bf16x8;
typedef __attribute__((ext_vector_type(4))) float f32x4;
typedef __attribute__((ext_vector_type(8))) unsigned short us8;

#define BN 65536   // T n-dimension (all 64 samples)

__device__ __forceinline__ unsigned short f2bf(float f) {
    unsigned u = __float_as_uint(f);
    u += 0x7fffu + ((u >> 16) & 1u);
    return (unsigned short)(u >> 16);
}
__device__ __forceinline__ float bf2f(unsigned short s) {
    return __uint_as_float(((unsigned)s) << 16);
}
__device__ __forceinline__ int floordiv3(int t) {
    return (t >= 0) ? (t / 3) : -((2 - t) / 3);
}

// ---- K0: merged prep: X transpose->bf16, W pack->bf16, stats zero --------
// blocks 0..1023: XbT; 1024..1311: A; 1312: stats.
__global__ __launch_bounds__(256) void k0_all(const float* __restrict__ x,
                                              const float* __restrict__ w,
                                              unsigned short* __restrict__ xbt,
                                              unsigned short* __restrict__ A,
                                              float* __restrict__ stats) {
    const int bid = blockIdx.x;
    const int tid = threadIdx.x;
    if (bid < 1024) {
        const int n = (bid & 15) * 64 + (tid & 63);
        const int cg = tid >> 6;
        const int b = bid >> 4;
        #pragma unroll
        for (int j2 = 0; j2 < 2; ++j2) {
            int c8 = cg * 2 + j2;                 // 0..7
            us8 r;
            #pragma unroll
            for (int j = 0; j < 8; ++j)
                r[j] = f2bf(x[(((b << 6) + c8 * 8 + j) << 10) + n]);
            *reinterpret_cast<us8*>(xbt + ((size_t)(b << 10) + n) * 64 + c8 * 8) = r;
        }
    } else if (bid < 1312) {
        int gid = (bid - 1024) * 256 + tid;       // < 73728
        int m = gid >> 6, c = gid & 63;
        int kk = m >> 7, o = m & 127;
        A[gid] = f2bf(w[(o * 64 + c) * 9 + kk]);
    } else {
        stats[tid] = 0.f;                          // 256 floats = sum+sumsq
    }
}

// ---- K1: GEMM A[1152x64] @ XbT^T[64 x 65536] -> T bf16 (R5 verbatim) -----
// grid (512 nt, 9 mt), 256 thr (2x2 wave grid), tile 128m x 128n, K=64.
__global__ __launch_bounds__(256) void k1_gemm(const unsigned short* __restrict__ XbT,
                                               const unsigned short* __restrict__ A,
                                               unsigned short* __restrict__ T) {
    __shared__ union {
        struct { us8 lA[8 * 129]; us8 lB[8 * 129]; } in;   // 33024 B
        unsigned short ot[128 * 132];                       // 33792 B
    } sm;
    const int tid = threadIdx.x;
    const int nt = blockIdx.x;    // 0..511
    const int mt = blockIdx.y;    // 0..8

    #pragma unroll
    for (int i = 0; i < 4; ++i) {
        int gid = i * 256 + tid;
        int row = gid >> 3, ch = gid & 7; // ch fastest -> coalesced 16B/lane
        sm.in.lA[ch * 129 + row] = *reinterpret_cast<const us8*>(
            A + (size_t)(mt * 128 + row) * 64 + ch * 8);
    }
    #pragma unroll
    for (int i = 0; i < 4; ++i) {
        int gid = i * 256 + tid;
        int row = gid >> 3, ch = gid & 7;
        sm.in.lB[ch * 129 + row] = *reinterpret_cast<const us8*>(
            XbT + ((size_t)nt * 128 + row) * 64 + ch * 8);
    }
    __syncthreads();

    const int wave = tid >> 6, lane = tid & 63;
    const int quad = lane >> 4, l15 = lane & 15;
    const int wm = wave & 1, wn = wave >> 1;
    const bf16x8* pA = reinterpret_cast<const bf16x8*>(sm.in.lA);
    const bf16x8* pB = reinterpret_cast<const bf16x8*>(sm.in.lB);

    f32x4 acc[4][4] = {};
    #pragma unroll
    for (int ks = 0; ks < 2; ++ks) {
        const int kg = ks * 4 + quad;
        bf16x8 aF[4], bF[4];
        #pragma unroll
        for (int mi = 0; mi < 4; ++mi)
            aF[mi] = pA[kg * 129 + wm * 64 + mi * 16 + l15];
        #pragma unroll
        for (int ni = 0; ni < 4; ++ni)
            bF[ni] = pB[kg * 129 + wn * 64 + ni * 16 + l15];
        #pragma unroll
        for (int mi = 0; mi < 4; ++mi)
            #pragma unroll
            for (int ni = 0; ni < 4; ++ni)
                acc[mi][ni] = __builtin_amdgcn_mfma_f32_16x16x32_bf16(aF[mi], bF[ni], acc[mi][ni], 0, 0, 0);
    }
    __syncthreads();   // frags consumed; reuse LDS for output tile

    {
        const int mloc = wm * 64 + quad * 4;
        const int nloc = wn * 64 + l15;
        #pragma unroll
        for (int mi = 0; mi < 4; ++mi)
            #pragma unroll
            for (int r = 0; r < 4; ++r) {
                unsigned short* dst = &sm.ot[(mloc + mi * 16 + r) * 132 + nloc];
                #pragma unroll
                for (int ni = 0; ni < 4; ++ni)
                    dst[ni * 16] = f2bf(acc[mi][ni][r]);
            }
    }
    __syncthreads();

    #pragma unroll
    for (int i = 0; i < 8; ++i) {
        int cid = i * 256 + tid;
        int row = cid >> 4, ch = cid & 15;
        us8 v = *reinterpret_cast<const us8*>(&sm.ot[row * 132 + ch * 8]);
        *reinterpret_cast<us8*>(T + (size_t)(mt * 128 + row) * BN + (size_t)nt * 128 + ch * 8) = v;
    }
}

// ---- K2: LDS-staged 36-tap gather + maxpool3 + bias + BN stats -----------
// grid (o=128, b=64), 512 thr, 2 outputs/thread (p and p+16). LDS: 9 planes
// of 33 rows x 40 f32 (4-col pads both sides, row 32 = zeros).
#define PLS (33 * 40)
__global__ __launch_bounds__(512) void k2_gather(const unsigned short* __restrict__ T,
                                                 const float* __restrict__ bias,
                                                 const int* __restrict__ hh,
                                                 const int* __restrict__ ww,
                                                 float* __restrict__ out,
                                                 float* __restrict__ stats) {
    __shared__ float lt[9 * PLS + 4];
    __shared__ float red[16];
    const int tid = threadIdx.x;
    const int o = blockIdx.x, b = blockIdx.y;

    // zero pad columns (rows 0..31, cols {0..3, 36..39})
    #pragma unroll
    for (int it = 0; it < 5; ++it) {
        int i = it * 512 + tid;
        if (i < 9 * 32 * 8) {
            int pr = i >> 3, c = i & 7;
            int kk = pr >> 5, r = pr & 31;
            lt[kk * PLS + r * 40 + (c < 4 ? c : c + 32)] = 0.f;
        }
    }
    // zero row 32 of each plane; slack zeroed separately (in-bounds)
    if (tid < 9 * 40) {
        int kk = tid / 40, c = tid - kk * 40;
        lt[kk * PLS + 32 * 40 + c] = 0.f;
    }
    if (tid < 4) lt[9 * PLS + tid] = 0.f;
    // stage 9 planes (1024 bf16 contiguous each) -> f32 padded rows
    const unsigned short* Tb = T + (size_t)o * BN + (size_t)b * 1024;
    for (int i = tid; i < 9 * 128; i += 512) {
        int kk = i >> 7, c8 = i & 127;
        us8 v = *reinterpret_cast<const us8*>(Tb + (size_t)kk * 128 * BN + c8 * 8);
        int r = c8 >> 2, cb = (c8 & 3) * 8;
        float* dst = &lt[kk * PLS + r * 40 + 4 + cb];
        f32x4 lo, hi;
        lo[0] = bf2f(v[0]); lo[1] = bf2f(v[1]); lo[2] = bf2f(v[2]); lo[3] = bf2f(v[3]);
        hi[0] = bf2f(v[4]); hi[1] = bf2f(v[5]); hi[2] = bf2f(v[6]); hi[3] = bf2f(v[7]);
        *reinterpret_cast<f32x4*>(dst) = lo;
        *reinterpret_cast<f32x4*>(dst + 4) = hi;
    }
    __syncthreads();

    int dh = 96 / hh[b]; if (dh < 1) dh = 1;
    int dw = 96 / ww[b]; if (dw < 1) dw = 1;
    const int q = tid & 31, pbase = tid >> 5;   // pbase 0..15
    const int qoff = q + 4;

    // ki=1 / kj=1 have t0=0 -> base 0, selector always 0.
    const int g0 = floordiv3(-dh), g2 = floordiv3(dh);
    const int f0 = floordiv3(-dw), f2 = floordiv3(dw);
    int r0sel[3], r2sel[3], c0sel[3], c2sel[3];    // block-uniform {0,1}
    #pragma unroll
    for (int t = 0; t < 3; ++t) {
        r0sel[t] = floordiv3(t - dh) - g0;
        r2sel[t] = floordiv3(t + dh) - g2;
        c0sel[t] = floordiv3(t - dw) - f0;
        c2sel[t] = floordiv3(t + dw) - f2;
    }
    const float bias_o = bias[o];
    float s1 = 0.f, s2 = 0.f;

    #pragma unroll
    for (int half = 0; half < 2; ++half) {
        const int p = pbase + half * 16;
        int rA0 = p + g0;     rA0 = ((unsigned)rA0 < 32u) ? rA0 : 32;
        int rB0 = p + g0 + 1; rB0 = ((unsigned)rB0 < 32u) ? rB0 : 32;
        int rA2 = p + g2;     rA2 = ((unsigned)rA2 < 32u) ? rA2 : 32;
        int rB2 = p + g2 + 1; rB2 = ((unsigned)rB2 < 32u) ? rB2 : 32;

        float u0[2][3], u1[3], u2[2][3];
        {   // ki = 0 (planes 0..2)
            const float* pl0 = &lt[0 * PLS + qoff + f0];
            const float* pl1 = &lt[1 * PLS + qoff];
            const float* pl2 = &lt[2 * PLS + qoff + f2];
            float pA0a = pl0[rA0 * 40], pA0b = pl0[rA0 * 40 + 1];
            float pB0a = pl0[rB0 * 40], pB0b = pl0[rB0 * 40 + 1];
            float sA   = pl1[rA0 * 40], sB   = pl1[rB0 * 40];
            float pA2a = pl2[rA0 * 40], pA2b = pl2[rA0 * 40 + 1];
            float pB2a = pl2[rB0 * 40], pB2b = pl2[rB0 * 40 + 1];
            #pragma unroll
            for (int x3 = 0; x3 < 3; ++x3) {
                u0[0][x3] = (c0sel[x3] ? pA0b : pA0a) + sA + (c2sel[x3] ? pA2b : pA2a);
                u0[1][x3] = (c0sel[x3] ? pB0b : pB0a) + sB + (c2sel[x3] ? pB2b : pB2a);
            }
        }
        {   // ki = 1 (planes 3..5), row p only
            const float* pl0 = &lt[3 * PLS + qoff + f0];
            const float* pl1 = &lt[4 * PLS + qoff];
            const float* pl2 = &lt[5 * PLS + qoff + f2];
            float pa = pl0[p * 40], pb = pl0[p * 40 + 1];
            float s  = pl1[p * 40];
            float ra = pl2[p * 40], rb = pl2[p * 40 + 1];
            #pragma unroll
            for (int x3 = 0; x3 < 3; ++x3)
                u1[x3] = (c0sel[x3] ? pb : pa) + s + (c2sel[x3] ? rb : ra);
        }
        {   // ki = 2 (planes 6..8)
            const float* pl0 = &lt[6 * PLS + qoff + f0];
            const float* pl1 = &lt[7 * PLS + qoff];
            const float* pl2 = &lt[8 * PLS + qoff + f2];
            float pA0a = pl0[rA2 * 40], pA0b = pl0[rA2 * 40 + 1];
            float pB0a = pl0[rB2 * 40], pB0b = pl0[rB2 * 40 + 1];
            float sA   = pl1[rA2 * 40], sB   = pl1[rB2 * 40];
            float pA2a = pl2[rA2 * 40], pA2b = pl2[rA2 * 40 + 1];
            float pB2a = pl2[rB2 * 40], pB2b = pl2[rB2 * 40 + 1];
            #pragma unroll
            for (int x3 = 0; x3 < 3; ++x3) {
                u2[0][x3] = (c0sel[x3] ? pA0b : pA0a) + sA + (c2sel[x3] ? pA2b : pA2a);
                u2[1][x3] = (c0sel[x3] ? pB0b : pB0a) + sB + (c2sel[x3] ? pB2b : pB2a);
            }
        }

        float best = -3.4e38f;
        #pragma unroll
        for (int y3 = 0; y3 < 3; ++y3)
            #pragma unroll
            for (int x3 = 0; x3 < 3; ++x3) {
                float s = (r0sel[y3] ? u0[1][x3] : u0[0][x3])
                        + u1[x3]
                        + (r2sel[y3] ? u2[1][x3] : u2[0][x3]);
                best = fmaxf(best, s);
            }
        float val = best + bias_o;
        out[(((size_t)b * 128 + o) * 32 + p) * 32 + q] = val;
        s1 += val;
        s2 += val * val;
    }

    // stats: wave reduce -> LDS -> block reduce -> 2 atomics
    #pragma unroll
    for (int m = 32; m >= 1; m >>= 1) {
        s1 += __shfl_xor(s1, m, 64);
        s2 += __shfl_xor(s2, m, 64);
    }
    if ((tid & 63) == 0) {
        red[tid >> 6] = s1;
        red[8 + (tid >> 6)] = s2;
    }
    __syncthreads();
    if (tid < 64) {
        float a1 = (tid < 8) ? red[tid] : 0.f;
        float a2 = (tid < 8) ? red[8 + tid] : 0.f;
        #pragma unroll
        for (int m = 4; m >= 1; m >>= 1) {
            a1 += __shfl_xor(a1, m, 64);
            a2 += __shfl_xor(a2, m, 64);
        }
        if (tid == 0) {
            atomicAdd(&stats[o], a1);
            atomicAdd(&stats[128 + o], a2);
        }
    }
}

// ---- K3: BN finalize + affine + relu, in-place on d_out ------------------
__global__ __launch_bounds__(256) void k3_bn(float4* __restrict__ out,
                                             const float* __restrict__ stats,
                                             const float* __restrict__ gamma,
                                             const float* __restrict__ beta) {
    int i4 = blockIdx.x * 256 + threadIdx.x;   // 0..2097151
    int o = (i4 >> 8) & 127;
    const float invN = 1.0f / 65536.0f;
    float mean = stats[o] * invN;
    float var = stats[128 + o] * invN - mean * mean;
    float inv = rsqrtf(var + 1e-5f);
    float sc = gamma[o] * inv;
    float sh = beta[o] - mean * sc;
    float4 v = out[i4];
    v.x = fmaxf(fmaf(v.x, sc, sh), 0.f);
    v.y = fmaxf(fmaf(v.y, sc, sh), 0.f);
    v.z = fmaxf(fmaf(v.z, sc, sh), 0.f);
    v.w = fmaxf(fmaf(v.w, sc, sh), 0.f);
    out[i4] = v;
}

extern "C" void kernel_launch(void* const* d_in, const int* in_sizes, int n_in,
                              void* d_out, int out_size, void* d_ws, size_t ws_size,
                              hipStream_t stream) {
    const float* x     = (const float*)d_in[0];
    const int*   h     = (const int*)d_in[1];
    const int*   w     = (const int*)d_in[2];
    const float* wt    = (const float*)d_in[3];
    const float* bias  = (const float*)d_in[4];
    const float* gamma = (const float*)d_in[5];
    const float* beta  = (const float*)d_in[6];
    float* out = (float*)d_out;
    char* ws = (char*)d_ws;

    float*          stats = (float*)(ws + 0);
    unsigned short* A     = (unsigned short*)(ws + 4096);
    unsigned short* XbT   = (unsigned short*)(ws + 151552);
    unsigned short* T     = (unsigned short*)(ws + 8540160);

    k0_all<<<1313, 256, 0, stream>>>(x, wt, XbT, A, stats);
    k1_gemm<<<dim3(512, 9), 256, 0, stream>>>(XbT, A, T);
    k2_gather<<<dim3(128, 64), 512, 0, stream>>>(T, bias, h, w, out, stats);
    k3_bn<<<8192, 256, 0, stream>>>((float4*)out, stats, gamma, beta);
}